// Round 1
// baseline (643.101 us; speedup 1.0000x reference)
//
#include <hip/hip_runtime.h>

#define T_LEN 65536
#define XD 64
#define GS 17      // LDS row stride for 16x16 tiles
#define DSTR 68    // LDS row stride for staged data rows
#define K2 128     // chunk size for stage 2
#define W2 64      // warm-up window for stage 2
#define PF 8       // prefetch depth for stage 2

__global__ __launch_bounds__(256, 2)
void vilds_stage1(const float* __restrict__ data,
                  const float* __restrict__ Wmu, const float* __restrict__ bmu,
                  const float* __restrict__ WL,  const float* __restrict__ bL,
                  const float* __restrict__ WLx, const float* __restrict__ bLx,
                  const float* __restrict__ ns,
                  float* __restrict__ Nbuf, float* __restrict__ Ubuf,
                  float* __restrict__ PXbuf, float* __restrict__ entOut)
{
    __shared__ float Dl[17 * DSTR];
    __shared__ float Al[16 * 16 * GS];
    __shared__ float Gl[16 * 16 * GS];
    __shared__ float Pl[16 * 16 * GS];

    const int tid = threadIdx.x;
    const int g16 = tid >> 4;   // t-group within block (0..15)
    const int li  = tid & 15;   // row/column owned by this lane
    const int t0  = blockIdx.x * 16;
    const int t   = t0 + g16;

    // stage data rows t0 .. t0+16 (row t+1 needed for BBChol)
    for (int idx = tid; idx < 17 * XD; idx += 256) {
        int r = idx >> 6, k = idx & 63;
        int tr = t0 + r;
        Dl[r * DSTR + k] = (tr < T_LEN) ? data[(size_t)tr * XD + k] : 0.0f;
    }
    __syncthreads();

    // ---- recognition GEMM: a = row li of AAChol_t, bt = row li of BBChol_t ----
    float a[16], bt[16];
    float px = bmu[li];
    #pragma unroll
    for (int j = 0; j < 16; ++j) {
        a[j]  = bL [li * 16 + j] + ((j == li) ? 3.0f : 0.0f);
        bt[j] = bLx[li * 16 + j];
    }
    {
        const float* drow = &Dl[g16 * DSTR];
        const float4* WL4  = (const float4*)WL;
        const float4* WLx4 = (const float4*)WLx;
        #pragma unroll 4
        for (int k = 0; k < XD; ++k) {
            float dk  = drow[k];          // data[t][k]
            float dk2 = drow[DSTR + k];   // data[t+1][k] (zero-padded at t=T-1)
            px = fmaf(dk, Wmu[k * 16 + li], px);
            #pragma unroll
            for (int c = 0; c < 4; ++c) {
                float4 w = WL4[k * 64 + li * 4 + c];
                a[4*c+0] = fmaf(dk, w.x, a[4*c+0]);
                a[4*c+1] = fmaf(dk, w.y, a[4*c+1]);
                a[4*c+2] = fmaf(dk, w.z, a[4*c+2]);
                a[4*c+3] = fmaf(dk, w.w, a[4*c+3]);
                float4 v = WLx4[k * 64 + li * 4 + c];
                bt[4*c+0] = fmaf(dk2, v.x, bt[4*c+0]);
                bt[4*c+1] = fmaf(dk2, v.y, bt[4*c+1]);
                bt[4*c+2] = fmaf(dk2, v.z, bt[4*c+2]);
                bt[4*c+3] = fmaf(dk2, v.w, bt[4*c+3]);
            }
        }
    }

    // share A rows
    #pragma unroll
    for (int j = 0; j < 16; ++j) Al[(g16*16 + li)*GS + j] = a[j];
    __syncthreads();

    // ---- S = A A^T + 1e-6 I  (lane li holds row li) ----
    float s[16];
    #pragma unroll
    for (int j = 0; j < 16; ++j) {
        float acc = (j == li) ? 1e-6f : 0.0f;
        const float* Arow = &Al[(g16*16 + j)*GS];
        #pragma unroll
        for (int k = 0; k < 16; ++k) acc = fmaf(a[k], Arow[k], acc);
        s[j] = acc;
    }

    // ---- Cholesky G of S: rows distributed across the 16 lanes ----
    float g[16], invd[16];
    float ent = 0.0f;
    #pragma unroll
    for (int k = 0; k < 16; ++k) {
        float dkk = __shfl(s[k], k, 16);   // residual diagonal from lane k
        dkk = fmaxf(dkk, 1e-20f);
        if (li == k) ent += 0.5f * logf(dkk);   // log(G[k][k])
        float inv = 1.0f / sqrtf(dkk);
        invd[k] = inv;
        g[k] = s[k] * inv;                 // G[li][k] (valid for li>=k)
        #pragma unroll
        for (int j = k + 1; j < 16; ++j) {
            float bcj = __shfl(g[k], j, 16);   // G[j][k]
            s[j] = fmaf(-g[k], bcj, s[j]);     // trailing update
        }
    }
    #pragma unroll
    for (int j = 0; j < 16; ++j) Gl[(g16*16 + li)*GS + j] = g[j];
    __syncthreads();

    // ---- P^T = G^{-1} A : lane li solves column li (forward substitution) ----
    float p[16];
    #pragma unroll
    for (int i = 0; i < 16; ++i) {
        float acc = Al[(g16*16 + i)*GS + li];
        #pragma unroll
        for (int m = 0; m < i; ++m) acc = fmaf(-Gl[(g16*16 + i)*GS + m], p[m], acc);
        p[i] = acc * invd[i];
    }
    #pragma unroll
    for (int i = 0; i < 16; ++i) Pl[(g16*16 + li)*GS + i] = p[i];  // row li of P
    __syncthreads();

    // ---- C = BBChol * P : lane li holds row li ----
    float cr[16];
    #pragma unroll
    for (int j = 0; j < 16; ++j) {
        float acc = 0.0f;
        #pragma unroll
        for (int k = 0; k < 16; ++k) acc = fmaf(bt[k], Pl[(g16*16 + k)*GS + j], acc);
        cr[j] = acc;
    }

    // ---- N = -G^{-T} C^T (lane li = column li) and u = G^{-T} b (all lanes) ----
    float n[16], uu[16];
    #pragma unroll
    for (int ii = 0; ii < 16; ++ii) {
        const int i = 15 - ii;
        float accN = -cr[i];
        float accU = ns[(size_t)t * 16 + i];
        #pragma unroll
        for (int m = i + 1; m < 16; ++m) {
            float gmi = Gl[(g16*16 + m)*GS + i];
            accN = fmaf(-gmi, n[m], accN);
            accU = fmaf(-gmi, uu[m], accU);
        }
        n[i]  = accN * invd[i];
        uu[i] = accU * invd[i];
    }

    if (t < T_LEN - 1) {
        #pragma unroll
        for (int i = 0; i < 16; ++i)
            Nbuf[(size_t)t * 256 + i * 16 + li] = n[i];   // row-major N[t][i][j]
    }
    if (li == 0) {
        float4* U4 = (float4*)&Ubuf[(size_t)t * 16];
        U4[0] = make_float4(uu[0],  uu[1],  uu[2],  uu[3]);
        U4[1] = make_float4(uu[4],  uu[5],  uu[6],  uu[7]);
        U4[2] = make_float4(uu[8],  uu[9],  uu[10], uu[11]);
        U4[3] = make_float4(uu[12], uu[13], uu[14], uu[15]);
    }
    PXbuf[(size_t)t * 16 + li] = px;

    // ---- entropy: block reduce, one atomic per block ----
    __syncthreads();
    Dl[tid] = ent;
    __syncthreads();
    for (int s2 = 128; s2 > 0; s2 >>= 1) {
        if (tid < s2) Dl[tid] += Dl[tid + s2];
        __syncthreads();
    }
    if (tid == 0) atomicAdd(entOut, -Dl[0]);
}

// Backward recurrence x_t = u_t + N_t x_{t+1}, chunked with warm-up window.
__global__ __launch_bounds__(64, 1)
void vilds_stage2(const float* __restrict__ Nbuf, const float* __restrict__ Ubuf,
                  const float* __restrict__ PXbuf, float* __restrict__ out)
{
    const int lane = threadIdx.x;
    const int i  = lane & 15;   // output row
    const int gq = lane >> 4;   // k-quarter (4 columns each)
    const int a  = blockIdx.x * K2;
    int ts = a + K2 - 1 + W2;
    if (ts > T_LEN - 1) ts = T_LEN - 1;

    float x = Ubuf[(size_t)ts * 16 + i];   // exact at t=T-1, truncated start otherwise
    if (ts < a + K2 && gq == 0)
        out[1 + (size_t)ts * 16 + i] = x + PXbuf[(size_t)ts * 16 + i];

    float4 nb[PF]; float ub[PF], pxb[PF];
    #pragma unroll
    for (int q = 0; q < PF; ++q) {
        int tt = ts - 1 - q;
        if (tt >= a) {
            nb[q]  = *(const float4*)&Nbuf[(size_t)tt * 256 + i * 16 + gq * 4];
            ub[q]  = Ubuf[(size_t)tt * 16 + i];
            pxb[q] = PXbuf[(size_t)tt * 16 + i];
        }
    }

    for (int tb = ts - 1; tb >= a; tb -= PF) {
        #pragma unroll
        for (int q = 0; q < PF; ++q) {
            int t = tb - q;
            if (t >= a) {
                float4 nr = nb[q]; float ut = ub[q]; float pxt = pxb[q];
                int tp = t - PF;
                if (tp >= a) {   // prefetch PF steps ahead
                    nb[q]  = *(const float4*)&Nbuf[(size_t)tp * 256 + i * 16 + gq * 4];
                    ub[q]  = Ubuf[(size_t)tp * 16 + i];
                    pxb[q] = PXbuf[(size_t)tp * 16 + i];
                }
                float x0 = __shfl(x, 4 * gq + 0, 16);
                float x1 = __shfl(x, 4 * gq + 1, 16);
                float x2 = __shfl(x, 4 * gq + 2, 16);
                float x3 = __shfl(x, 4 * gq + 3, 16);
                float pr = fmaf(nr.x, x0, nr.y * x1);
                pr = fmaf(nr.z, x2, pr);
                pr = fmaf(nr.w, x3, pr);
                pr += __shfl_xor(pr, 16);
                pr += __shfl_xor(pr, 32);
                x = ut + pr;                       // x_t[i], replicated over gq
                if (t < a + K2 && gq == 0)
                    out[1 + (size_t)t * 16 + i] = x + pxt;
            }
        }
    }
}

extern "C" void kernel_launch(void* const* d_in, const int* in_sizes, int n_in,
                              void* d_out, int out_size, void* d_ws, size_t ws_size,
                              hipStream_t stream)
{
    const float* data = (const float*)d_in[0];
    const float* Wmu  = (const float*)d_in[1];
    const float* bmu  = (const float*)d_in[2];
    const float* WL   = (const float*)d_in[3];
    const float* bL   = (const float*)d_in[4];
    const float* WLx  = (const float*)d_in[5];
    const float* bLx  = (const float*)d_in[6];
    const float* ns   = (const float*)d_in[7];
    float* out = (float*)d_out;

    float* ws    = (float*)d_ws;
    float* Nbuf  = ws;                               // T*256 floats
    float* Ubuf  = Nbuf + (size_t)T_LEN * 256;       // T*16
    float* PXbuf = Ubuf + (size_t)T_LEN * 16;        // T*16

    hipMemsetAsync(d_out, 0, sizeof(float), stream); // zero entropy accumulator
    vilds_stage1<<<dim3(T_LEN / 16), dim3(256), 0, stream>>>(
        data, Wmu, bmu, WL, bL, WLx, bLx, ns, Nbuf, Ubuf, PXbuf, out);
    vilds_stage2<<<dim3(T_LEN / K2), dim3(64), 0, stream>>>(Nbuf, Ubuf, PXbuf, out);
}

// Round 2
// 374.746 us; speedup vs baseline: 1.7161x; 1.7161x over previous
//
#include <hip/hip_runtime.h>
#include <math.h>

#define T_LEN 65536

#define DROW 72     // bf16 words per staged data row (64 + 8 pad, 16B-aligned rows)
#define TILE 332    // f32 words per 16x16 tile slot (row stride 20; 16B-aligned, bank-staggered)
#define RS   20     // f32 row stride inside a tile
#define K2   32     // stage-2 chunk length
#define W2   32     // stage-2 warm-up steps
#define PF   8      // stage-2 prefetch depth

typedef __attribute__((ext_vector_type(8))) short bh8;
typedef __attribute__((ext_vector_type(4))) float f4;

__device__ __forceinline__ short f2bf(float x) {
    union { float f; unsigned u; } v; v.f = x;
    return (short)((v.u + 0x7FFFu + ((v.u >> 16) & 1u)) >> 16);  // RNE
}

// ---- one-time weight swizzle into bf16 MFMA B-fragment order ----
// frag f = job*2 + ks (job 0..32, ks 0..1); element (lane, j):
//   B[k][n], k = ks*32 + (lane>>4)*8 + j, n = job*16 + (lane&15)
__global__ void wswz_kernel(const float* __restrict__ Wmu, const float* __restrict__ WL,
                            const float* __restrict__ WLx, short* __restrict__ Wsw)
{
    int idx = blockIdx.x * 256 + threadIdx.x;   // 0 .. 66*512-1
    int f = idx >> 9, r = idx & 511;
    int lane = r >> 3, j = r & 7;
    int ks = f & 1, job = f >> 1;
    int k = ks * 32 + ((lane >> 4) << 3) + j;
    int n = job * 16 + (lane & 15);
    float v = (n < 16) ? Wmu[k * 16 + n]
            : (n < 272) ? WL[k * 256 + (n - 16)]
            : WLx[k * 256 + (n - 272)];
    Wsw[idx] = f2bf(v);
}

// ---- fused: MFMA recognition GEMM -> LDS -> per-t factorization ----
__global__ __launch_bounds__(256, 3)
void vilds_fused(const float* __restrict__ data, const short* __restrict__ Wsw,
                 const float* __restrict__ bmu, const float* __restrict__ bL,
                 const float* __restrict__ bLx, const float* __restrict__ ns,
                 float* __restrict__ Nbuf, float* __restrict__ Ubuf,
                 float* __restrict__ PXbuf, float* __restrict__ entOut)
{
    __shared__ short Dt[17 * DROW];       // data rows t0..t0+16, bf16
    __shared__ float Atl[16 * TILE];      // AAChol tiles (later overwritten by P)
    __shared__ float Btl[16 * TILE];      // BBChol tiles (Braw[t0+1+g])

    const int tid = threadIdx.x;
    const int t0 = blockIdx.x * 16;

    // stage data rows t0..t0+16 as bf16 (row t0+16 needed for BBChol of t0+15)
    for (int idx = tid; idx < 17 * 16; idx += 256) {
        int row = idx >> 4, c4 = idx & 15;
        int tr = t0 + row;
        float4 dv = (tr < T_LEN) ? ((const float4*)data)[(size_t)tr * 16 + c4]
                                 : make_float4(0.f, 0.f, 0.f, 0.f);
        short4 b;
        b.x = f2bf(dv.x); b.y = f2bf(dv.y); b.z = f2bf(dv.z); b.w = f2bf(dv.w);
        *(short4*)&Dt[row * DROW + c4 * 4] = b;
    }
    __syncthreads();

    // ---- MFMA phase: jobs 0=postX, 1..16=A cols, 17..32=B cols ----
    {
        const int wv = tid >> 6, lane = tid & 63;
        const int col = lane & 15, quad = lane >> 4;
        for (int job = wv; job < 33; job += 4) {
            const int isB = (job >= 17);
            const int rowoff = isB ? 1 : 0;      // BBChol_t uses data[t+1]
            bh8 b0 = *(const bh8*)&Wsw[(job * 2 + 0) * 512 + lane * 8];
            bh8 b1 = *(const bh8*)&Wsw[(job * 2 + 1) * 512 + lane * 8];
            bh8 a0 = *(const bh8*)&Dt[(col + rowoff) * DROW + quad * 8];
            bh8 a1 = *(const bh8*)&Dt[(col + rowoff) * DROW + quad * 8 + 32];
            float bias;
            if (job == 0)      bias = bmu[col];
            else if (!isB)     bias = bL[(job - 1) * 16 + col] + ((col == job - 1) ? 3.0f : 0.0f);
            else               bias = bLx[(job - 17) * 16 + col];
            f4 acc = { bias, bias, bias, bias };
            acc = __builtin_amdgcn_mfma_f32_16x16x32_bf16(a0, b0, acc, 0, 0, 0);
            acc = __builtin_amdgcn_mfma_f32_16x16x32_bf16(a1, b1, acc, 0, 0, 0);
            // D layout: row = quad*4+r (the t within block), col = lane&15
            if (job == 0) {
                #pragma unroll
                for (int r = 0; r < 4; ++r)
                    PXbuf[(size_t)(t0 + quad * 4 + r) * 16 + col] = acc[r];
            } else if (!isB) {
                int i = job - 1;
                #pragma unroll
                for (int r = 0; r < 4; ++r)
                    Atl[(quad * 4 + r) * TILE + i * RS + col] = acc[r];
            } else {
                int i = job - 17;
                #pragma unroll
                for (int r = 0; r < 4; ++r)
                    Btl[(quad * 4 + r) * TILE + i * RS + col] = acc[r];
            }
        }
    }
    __syncthreads();

    // ---- factorization: group gg (16 lanes, all in one wave) handles t = t0+gg ----
    const int gg = tid >> 4, li = tid & 15;
    const int t = t0 + gg;
    float* At = &Atl[gg * TILE];
    const float* Bt_ = &Btl[gg * TILE];

    // own A row
    float a[16];
    #pragma unroll
    for (int c = 0; c < 4; ++c) {
        f4 v = *(const f4*)&At[li * RS + c * 4];
        a[4*c+0] = v[0]; a[4*c+1] = v[1]; a[4*c+2] = v[2]; a[4*c+3] = v[3];
    }

    // S = A A^T + 1e-6 I, row li
    float s[16];
    #pragma unroll
    for (int j = 0; j < 16; ++j) {
        f4 r0 = *(const f4*)&At[j * RS + 0];
        f4 r1 = *(const f4*)&At[j * RS + 4];
        f4 r2 = *(const f4*)&At[j * RS + 8];
        f4 r3 = *(const f4*)&At[j * RS + 12];
        float acc = (j == li) ? 1e-6f : 0.0f;
        acc = fmaf(a[0], r0[0], acc);  acc = fmaf(a[1], r0[1], acc);
        acc = fmaf(a[2], r0[2], acc);  acc = fmaf(a[3], r0[3], acc);
        acc = fmaf(a[4], r1[0], acc);  acc = fmaf(a[5], r1[1], acc);
        acc = fmaf(a[6], r1[2], acc);  acc = fmaf(a[7], r1[3], acc);
        acc = fmaf(a[8], r2[0], acc);  acc = fmaf(a[9], r2[1], acc);
        acc = fmaf(a[10], r2[2], acc); acc = fmaf(a[11], r2[3], acc);
        acc = fmaf(a[12], r3[0], acc); acc = fmaf(a[13], r3[1], acc);
        acc = fmaf(a[14], r3[2], acc); acc = fmaf(a[15], r3[3], acc);
        s[j] = acc;
    }

    // Cholesky G of S (lane li owns row li), shuffle-based
    float gr[16], invd[16];
    float ent = 0.0f;
    #pragma unroll
    for (int k = 0; k < 16; ++k) {
        float dkk = __shfl(s[k], k, 16);
        dkk = fmaxf(dkk, 1e-20f);
        if (li == k) ent += 0.5f * logf(dkk);
        float inv = 1.0f / sqrtf(dkk);
        invd[k] = inv;
        gr[k] = s[k] * inv;                    // G[li][k], valid li>=k
        #pragma unroll
        for (int j = k + 1; j < 16; ++j) {
            float bcj = __shfl(gr[k], j, 16);  // G[j][k]
            s[j] = fmaf(-gr[k], bcj, s[j]);
        }
    }

    // P^T = G^{-1} A: lane li solves column li; G[i][m] via shuffle (uniform idx)
    float p[16];
    #pragma unroll
    for (int i = 0; i < 16; ++i) {
        float acc = At[i * RS + li];           // A[i][li]
        #pragma unroll
        for (int m = 0; m < i; ++m)
            acc = fmaf(-__shfl(gr[m], i, 16), p[m], acc);
        p[i] = acc * invd[i];
    }
    // overwrite A tile with P (row li per lane); wave-synchronous, DS pipe in-order
    {
        f4 v0 = { p[0], p[1], p[2], p[3] };
        f4 v1 = { p[4], p[5], p[6], p[7] };
        f4 v2 = { p[8], p[9], p[10], p[11] };
        f4 v3 = { p[12], p[13], p[14], p[15] };
        *(f4*)&At[li * RS + 0]  = v0;
        *(f4*)&At[li * RS + 4]  = v1;
        *(f4*)&At[li * RS + 8]  = v2;
        *(f4*)&At[li * RS + 12] = v3;
    }

    // own BBChol row
    float bt[16];
    #pragma unroll
    for (int c = 0; c < 4; ++c) {
        f4 v = *(const f4*)&Bt_[li * RS + c * 4];
        bt[4*c+0] = v[0]; bt[4*c+1] = v[1]; bt[4*c+2] = v[2]; bt[4*c+3] = v[3];
    }

    // C = BBChol * P, row li  (read P rows broadcast)
    float cr[16];
    #pragma unroll
    for (int j = 0; j < 16; ++j) cr[j] = 0.0f;
    #pragma unroll
    for (int k = 0; k < 16; ++k) {
        f4 q0 = *(const f4*)&At[k * RS + 0];
        f4 q1 = *(const f4*)&At[k * RS + 4];
        f4 q2 = *(const f4*)&At[k * RS + 8];
        f4 q3 = *(const f4*)&At[k * RS + 12];
        float bk = bt[k];
        cr[0]  = fmaf(bk, q0[0], cr[0]);  cr[1]  = fmaf(bk, q0[1], cr[1]);
        cr[2]  = fmaf(bk, q0[2], cr[2]);  cr[3]  = fmaf(bk, q0[3], cr[3]);
        cr[4]  = fmaf(bk, q1[0], cr[4]);  cr[5]  = fmaf(bk, q1[1], cr[5]);
        cr[6]  = fmaf(bk, q1[2], cr[6]);  cr[7]  = fmaf(bk, q1[3], cr[7]);
        cr[8]  = fmaf(bk, q2[0], cr[8]);  cr[9]  = fmaf(bk, q2[1], cr[9]);
        cr[10] = fmaf(bk, q2[2], cr[10]); cr[11] = fmaf(bk, q2[3], cr[11]);
        cr[12] = fmaf(bk, q3[0], cr[12]); cr[13] = fmaf(bk, q3[1], cr[13]);
        cr[14] = fmaf(bk, q3[2], cr[14]); cr[15] = fmaf(bk, q3[3], cr[15]);
    }

    // N = -G^{-T} C^T (lane li = column li), u = G^{-T} b (replicated); G[m][i] via shuffle
    float n_[16], uu[16];
    #pragma unroll
    for (int ii = 0; ii < 16; ++ii) {
        const int i = 15 - ii;
        float accN = -cr[i];
        float accU = ns[(size_t)t * 16 + i];
        #pragma unroll
        for (int m = i + 1; m < 16; ++m) {
            float gmi = __shfl(gr[i], m, 16);   // G[m][i]
            accN = fmaf(-gmi, n_[m], accN);
            accU = fmaf(-gmi, uu[m], accU);
        }
        n_[i] = accN * invd[i];
        uu[i] = accU * invd[i];
    }

    if (t < T_LEN - 1) {
        #pragma unroll
        for (int i = 0; i < 16; ++i)
            Nbuf[(size_t)t * 256 + i * 16 + li] = n_[i];   // row-major N[t][i][j]
    }
    if (li == 0) {
        f4* U4 = (f4*)&Ubuf[(size_t)t * 16];
        f4 u0 = { uu[0], uu[1], uu[2], uu[3] };
        f4 u1 = { uu[4], uu[5], uu[6], uu[7] };
        f4 u2 = { uu[8], uu[9], uu[10], uu[11] };
        f4 u3 = { uu[12], uu[13], uu[14], uu[15] };
        U4[0] = u0; U4[1] = u1; U4[2] = u2; U4[3] = u3;
    }

    // entropy: reduce across the wave, one atomic per wave
    float esum = ent;
    #pragma unroll
    for (int off = 1; off < 64; off <<= 1)
        esum += __shfl_xor(esum, off, 64);
    if ((tid & 63) == 0) atomicAdd(entOut, -esum);
}

// ---- backward recurrence x_t = u_t + N_t x_{t+1}, overlapped chunks ----
__global__ __launch_bounds__(64, 1)
void vilds_stage2(const float* __restrict__ Nbuf, const float* __restrict__ Ubuf,
                  const float* __restrict__ PXbuf, float* __restrict__ out)
{
    const int lane = threadIdx.x;
    const int i  = lane & 15;   // output row
    const int gq = lane >> 4;   // k-quarter (4 columns each)
    const int a  = blockIdx.x * K2;
    int ts = a + K2 - 1 + W2;
    if (ts > T_LEN - 1) ts = T_LEN - 1;

    float x = Ubuf[(size_t)ts * 16 + i];   // exact at t=T-1, truncated start otherwise
    if (ts < a + K2 && gq == 0)
        out[1 + (size_t)ts * 16 + i] = x + PXbuf[(size_t)ts * 16 + i];

    float4 nb[PF]; float ub[PF], pxb[PF];
    #pragma unroll
    for (int q = 0; q < PF; ++q) {
        int tt = ts - 1 - q;
        if (tt >= a) {
            nb[q]  = *(const float4*)&Nbuf[(size_t)tt * 256 + i * 16 + gq * 4];
            ub[q]  = Ubuf[(size_t)tt * 16 + i];
            pxb[q] = PXbuf[(size_t)tt * 16 + i];
        }
    }

    for (int tb = ts - 1; tb >= a; tb -= PF) {
        #pragma unroll
        for (int q = 0; q < PF; ++q) {
            int t = tb - q;
            if (t >= a) {
                float4 nr = nb[q]; float ut = ub[q]; float pxt = pxb[q];
                int tp = t - PF;
                if (tp >= a) {
                    nb[q]  = *(const float4*)&Nbuf[(size_t)tp * 256 + i * 16 + gq * 4];
                    ub[q]  = Ubuf[(size_t)tp * 16 + i];
                    pxb[q] = PXbuf[(size_t)tp * 16 + i];
                }
                float x0 = __shfl(x, 4 * gq + 0, 16);
                float x1 = __shfl(x, 4 * gq + 1, 16);
                float x2 = __shfl(x, 4 * gq + 2, 16);
                float x3 = __shfl(x, 4 * gq + 3, 16);
                float pr = fmaf(nr.x, x0, nr.y * x1);
                pr = fmaf(nr.z, x2, pr);
                pr = fmaf(nr.w, x3, pr);
                pr += __shfl_xor(pr, 16);
                pr += __shfl_xor(pr, 32);
                x = ut + pr;                       // x_t[i], replicated over gq
                if (t < a + K2 && gq == 0)
                    out[1 + (size_t)t * 16 + i] = x + pxt;
            }
        }
    }
}

extern "C" void kernel_launch(void* const* d_in, const int* in_sizes, int n_in,
                              void* d_out, int out_size, void* d_ws, size_t ws_size,
                              hipStream_t stream)
{
    const float* data = (const float*)d_in[0];
    const float* Wmu  = (const float*)d_in[1];
    const float* bmu  = (const float*)d_in[2];
    const float* WL   = (const float*)d_in[3];
    const float* bL   = (const float*)d_in[4];
    const float* WLx  = (const float*)d_in[5];
    const float* bLx  = (const float*)d_in[6];
    const float* ns   = (const float*)d_in[7];
    float* out = (float*)d_out;

    float* ws    = (float*)d_ws;
    float* Nbuf  = ws;                               // T*256 floats
    float* Ubuf  = Nbuf + (size_t)T_LEN * 256;       // T*16
    float* PXbuf = Ubuf + (size_t)T_LEN * 16;        // T*16
    short* Wsw   = (short*)(PXbuf + (size_t)T_LEN * 16);  // 66*512 bf16

    hipMemsetAsync(d_out, 0, sizeof(float), stream); // zero entropy accumulator
    wswz_kernel<<<dim3(132), dim3(256), 0, stream>>>(Wmu, WL, WLx, Wsw);
    vilds_fused<<<dim3(T_LEN / 16), dim3(256), 0, stream>>>(
        data, Wsw, bmu, bL, bLx, ns, Nbuf, Ubuf, PXbuf, out);
    vilds_stage2<<<dim3(T_LEN / K2), dim3(64), 0, stream>>>(Nbuf, Ubuf, PXbuf, out);
}